// Round 11
// baseline (418.298 us; speedup 1.0000x reference)
//
#include <hip/hip_runtime.h>

// Problem constants
#define B_  64
#define S_  512
#define D_  768
#define H_  768
#define C_  5
#define M_  (B_ * S_)        // 32768 rows

typedef float f32x4 __attribute__((ext_vector_type(4)));
typedef short short8 __attribute__((ext_vector_type(8)));   // bf16x8 MFMA operand

#define W1T_ELEMS (D_ * H_)          // 589824  (bf16: 1.18 MB)
#define PART2_ELEMS (2 * M_ * C_)    // 327680 floats = 1.31 MB

__device__ __forceinline__ unsigned short f2bf(float f) {
    unsigned int u = __float_as_uint(f);
    u += 0x7FFFu + ((u >> 16) & 1u);     // RNE
    return (unsigned short)(u >> 16);
}

// =========================================================================
// prep: W1 [k][n] fp32 -> w1t [n][k] bf16 (LDS-tiled transpose). ~3 us.
// =========================================================================
__global__ __launch_bounds__(256) void prep_w1_kernel(
    const float* __restrict__ W1, unsigned short* __restrict__ w1t)
{
    __shared__ float t[32][33];
    const int bx = blockIdx.x, by = blockIdx.y;
    const int lx = threadIdx.x & 31, ly = threadIdx.x >> 5;
    #pragma unroll
    for (int j = 0; j < 4; ++j)
        t[ly + 8 * j][lx] = W1[(by * 32 + ly + 8 * j) * H_ + bx * 32 + lx];
    __syncthreads();
    #pragma unroll
    for (int j = 0; j < 4; ++j)
        w1t[(size_t)(bx * 32 + ly + 8 * j) * D_ + by * 32 + lx] = f2bf(t[lx][ly + 8 * j]);
}

__global__ __launch_bounds__(256) void init_pot_kernel(
    const float* __restrict__ b2, const float* __restrict__ lb,
    const float* __restrict__ rb, float* __restrict__ pot)
{
    const int idx = blockIdx.x * 256 + threadIdx.x;
    if (idx < M_ * C_) {
        const int c = idx % C_;
        const int t = (idx / C_) & (S_ - 1);
        float v = b2[c];
        if (t == 0)      v += lb[c];
        if (t == S_ - 1) v += rb[c];
        pot[idx] = v;
    }
}

// =========================================================================
// Kernel 2 (R11): 256 rows x half-N (384 cols) per block, 1024 threads.
//
// Byte equation (R0-R10 model: dur = VMEM-instruction bytes / eff-rate):
//   bytes = X*(768/Ncols) + 1.18MB*(M/R).  R10 (128,384)=503MB -> 115us
//   at ~7 B/cy/CU.  R11 doubles R: (256,384)=351MB.  16 waves = 2 row-
//   groups x 8 col-groups; wave tile stays 128x48 (proven acc[8][3],
//   96 VGPR).  A: 2x32KB LDS dbuf, fp32->bf16 in-register staging with
//   async split (issue loads -> compute -> cvt+ds_write -> bar); barrier
//   count per staged byte halves vs R10.  B streamed L2->regs (w1t
//   1.18MB L2-hot).  Output: wave partials -> pp LDS -> plain stores to
//   part[2][M][5]; reduce_pot folds b2/boundaries.  No atomics.
// =========================================================================
__global__ __launch_bounds__(1024) void gemm_r256_kernel(
    const float* __restrict__ X,              // [M_, D_] fp32
    const unsigned short* __restrict__ w1t,   // [H_, D_] bf16 (n-major)
    const float* __restrict__ b1,
    const float* __restrict__ W2,             // [H_, C_]
    float* __restrict__ part)                 // [2][M_][C_] partials
{
    // A tile: [2 buf][256 rows x 64 k] bf16, 32 subtiles of 512 shorts:
    //   off = ((row>>4)*2 + (k>>5))*512 + (((k>>3)&3)*16 + (row&15))*8
    __shared__ __align__(16) unsigned short At[2][16384];   // 64 KB
    __shared__ float pp[8][256][C_];                        // 40 KB

    const int tid  = threadIdx.x;
    const int lane = tid & 63, w = tid >> 6;       // wave 0..15
    const int i15  = lane & 15, quad = lane >> 4;
    const int wrow = w >> 3, wcol = w & 7;         // 2 row-groups x 8 col-groups

    const int bid  = blockIdx.x;
    const int nh   = bid & 1;           // n-half 0..1
    const int rg   = bid >> 1;          // row-group 0..127
    const int rowb = rg * 256;
    const int ncol0 = nh * 384 + wcol * 48;   // wave's first col

    // B pointers: wave owns cols [ncol0, ncol0+48), 3 n-frags
    const unsigned short* bw[3];
    #pragma unroll
    for (int ni = 0; ni < 3; ++ni)
        bw[ni] = w1t + (size_t)(ncol0 + ni * 16 + i15) * D_ + quad * 8;

    // A staging map: thread handles (row = tid>>2, 16 k-floats at (tid&3)*16)
    const int arow = tid >> 2;              // 0..255
    const int ak4  = tid & 3;               // k-quarter of the 64-k tile
    const float* aSrc = X + (size_t)(rowb + arow) * D_ + ak4 * 16;
    const int o0 = ak4 * 2, o1 = ak4 * 2 + 1;   // two k-octets
    const int dst0 = ((arow >> 4) * 2 + (o0 >> 2)) * 512 + ((o0 & 3) * 16 + (arow & 15)) * 8;
    const int dst1 = ((arow >> 4) * 2 + (o1 >> 2)) * 512 + ((o1 & 3) * 16 + (arow & 15)) * 8;

    f32x4 acc[8][3];
    #pragma unroll
    for (int mi = 0; mi < 8; ++mi)
        #pragma unroll
        for (int ni = 0; ni < 3; ++ni)
            acc[mi][ni] = (f32x4){0.f, 0.f, 0.f, 0.f};

    // ---- prologue: stage tile 0 into buf 0 ----
    {
        const float4 xa = *(const float4*)(aSrc);
        const float4 xb = *(const float4*)(aSrc + 4);
        const float4 xc = *(const float4*)(aSrc + 8);
        const float4 xd = *(const float4*)(aSrc + 12);
        union { unsigned short u[8]; uint4 v; } p, q;
        p.u[0] = f2bf(xa.x); p.u[1] = f2bf(xa.y); p.u[2] = f2bf(xa.z); p.u[3] = f2bf(xa.w);
        p.u[4] = f2bf(xb.x); p.u[5] = f2bf(xb.y); p.u[6] = f2bf(xb.z); p.u[7] = f2bf(xb.w);
        q.u[0] = f2bf(xc.x); q.u[1] = f2bf(xc.y); q.u[2] = f2bf(xc.z); q.u[3] = f2bf(xc.w);
        q.u[4] = f2bf(xd.x); q.u[5] = f2bf(xd.y); q.u[6] = f2bf(xd.z); q.u[7] = f2bf(xd.w);
        *(uint4*)&At[0][dst0] = p.v;
        *(uint4*)&At[0][dst1] = q.v;
    }
    __syncthreads();

    // ---- main loop: 12 K-tiles of 64 ----
    for (int kt = 0; kt < 12; ++kt) {
        const int cur = kt & 1;
        const bool pre = (kt < 11);

        // async-split: issue next tile's global loads first
        float4 xa, xb, xc, xd;
        if (pre) {
            const float* s = aSrc + (kt + 1) * 64;
            xa = *(const float4*)(s);
            xb = *(const float4*)(s + 4);
            xc = *(const float4*)(s + 8);
            xd = *(const float4*)(s + 12);
        }

        // compute current tile (latency of the above hides under this)
        #pragma unroll
        for (int kh = 0; kh < 2; ++kh) {
            short8 af[8], bfr[3];
            #pragma unroll
            for (int mi = 0; mi < 8; ++mi)
                af[mi] = *(const short8*)
                    &At[cur][((wrow * 8 + mi) * 2 + kh) * 512 + lane * 8];
            #pragma unroll
            for (int ni = 0; ni < 3; ++ni)
                bfr[ni] = *(const short8*)(bw[ni] + kt * 64 + kh * 32);
            #pragma unroll
            for (int ni = 0; ni < 3; ++ni)
                #pragma unroll
                for (int mi = 0; mi < 8; ++mi)
                    acc[mi][ni] = __builtin_amdgcn_mfma_f32_16x16x32_bf16(
                        af[mi], bfr[ni], acc[mi][ni], 0, 0, 0);
        }

        // convert + write next tile into the other buffer
        if (pre) {
            union { unsigned short u[8]; uint4 v; } p, q;
            p.u[0] = f2bf(xa.x); p.u[1] = f2bf(xa.y); p.u[2] = f2bf(xa.z); p.u[3] = f2bf(xa.w);
            p.u[4] = f2bf(xb.x); p.u[5] = f2bf(xb.y); p.u[6] = f2bf(xb.z); p.u[7] = f2bf(xb.w);
            q.u[0] = f2bf(xc.x); q.u[1] = f2bf(xc.y); q.u[2] = f2bf(xc.z); q.u[3] = f2bf(xc.w);
            q.u[4] = f2bf(xd.x); q.u[5] = f2bf(xd.y); q.u[6] = f2bf(xd.z); q.u[7] = f2bf(xd.w);
            *(uint4*)&At[cur ^ 1][dst0] = p.v;
            *(uint4*)&At[cur ^ 1][dst1] = q.v;
        }
        __syncthreads();
    }

    // ---- epilogue: relu(h+b1)@W2, wave-partial -> pp -> part store ----
    float b1v[3], w2v[3][C_];
    #pragma unroll
    for (int ni = 0; ni < 3; ++ni) {
        const int col = ncol0 + ni * 16 + i15;
        b1v[ni] = b1[col];
        #pragma unroll
        for (int cc = 0; cc < C_; ++cc) w2v[ni][cc] = W2[col * C_ + cc];
    }

    #pragma unroll
    for (int mi = 0; mi < 8; ++mi) {
        float ps[4][C_];
        #pragma unroll
        for (int r = 0; r < 4; ++r)
            #pragma unroll
            for (int cc = 0; cc < C_; ++cc) ps[r][cc] = 0.f;

        #pragma unroll
        for (int ni = 0; ni < 3; ++ni)
            #pragma unroll
            for (int r = 0; r < 4; ++r) {
                float hh = acc[mi][ni][r] + b1v[ni];
                hh = hh > 0.f ? hh : 0.f;
                #pragma unroll
                for (int cc = 0; cc < C_; ++cc)
                    ps[r][cc] = fmaf(hh, w2v[ni][cc], ps[r][cc]);
            }

        // reduce over the 16 cols held across i15 lanes (quad = rows)
        #pragma unroll
        for (int off = 1; off < 16; off <<= 1)
            #pragma unroll
            for (int r = 0; r < 4; ++r)
                #pragma unroll
                for (int cc = 0; cc < C_; ++cc)
                    ps[r][cc] += __shfl_xor(ps[r][cc], off, 64);

        if (i15 == 0) {
            #pragma unroll
            for (int r = 0; r < 4; ++r) {
                const int row = wrow * 128 + mi * 16 + quad * 4 + r;   // 0..255
                #pragma unroll
                for (int cc = 0; cc < C_; ++cc)
                    pp[wcol][row][cc] = ps[r][cc];
            }
        }
    }
    __syncthreads();

    for (int idx = tid; idx < 256 * C_; idx += 1024) {
        const int row = idx / C_, cc = idx % C_;
        float s = 0.f;
        #pragma unroll
        for (int wv = 0; wv < 8; ++wv)
            s += pp[wv][row][cc];
        part[((size_t)nh * M_ + rowb + row) * C_ + cc] = s;
    }
}

// =========================================================================
// Kernel 2b: reduce 2 partials + b2/boundaries -> pot
// =========================================================================
__global__ __launch_bounds__(256) void reduce_pot_kernel(
    const float* __restrict__ part, const float* __restrict__ b2,
    const float* __restrict__ lb, const float* __restrict__ rb,
    float* __restrict__ pot)
{
    const int idx = blockIdx.x * 256 + threadIdx.x;
    if (idx < M_ * C_) {
        const int c = idx % C_;
        const int t = (idx / C_) & (S_ - 1);
        float v = b2[c];
        if (t == 0)      v += lb[c];
        if (t == S_ - 1) v += rb[c];
        v += part[idx] + part[(size_t)(M_ * C_) + idx];
        pot[idx] = v;
    }
}

// =========================================================================
// Last-resort fp32 GEMM if ws too small
// =========================================================================
#define FBK 8
#define FLDS 132
__global__ __launch_bounds__(256) void gemm_relu_pot_kernel(
    const float* __restrict__ X, const float* __restrict__ W1,
    const float* __restrict__ b1, const float* __restrict__ W2,
    float* __restrict__ pot)
{
    __shared__ float As[FBK * FLDS];
    __shared__ float Bs[FBK * FLDS];
    __shared__ float w2s[128][C_];

    const int tid = threadIdx.x;
    const int tx = tid & 15, ty = tid >> 4;
    const int m0 = blockIdx.y * 128, n0 = blockIdx.x * 128;

    for (int idx = tid; idx < 128 * C_; idx += 256)
        w2s[idx / C_][idx % C_] = W2[(n0 + idx / C_) * C_ + idx % C_];

    float acc[2][2][4][4];
    #pragma unroll
    for (int a = 0; a < 2; ++a)
        #pragma unroll
        for (int b = 0; b < 2; ++b)
            #pragma unroll
            for (int i = 0; i < 4; ++i)
                #pragma unroll
                for (int j = 0; j < 4; ++j) acc[a][b][i][j] = 0.f;

    const int arow = tid >> 1, aq = tid & 1;
    const int brow = tid >> 5, bq = tid & 31;
    const float* Aptr = X + (m0 + arow) * D_ + aq * 4;
    const float* Bptr = W1 + brow * H_ + n0 + bq * 4;

    for (int kt = 0; kt < D_; kt += FBK) {
        const float4 avv = *(const float4*)Aptr;
        const float4 bvv = *(const float4*)Bptr;
        __syncthreads();
        As[(aq * 4 + 0) * FLDS + arow] = avv.x;
        As[(aq * 4 + 1) * FLDS + arow] = avv.y;
        As[(aq * 4 + 2) * FLDS + arow] = avv.z;
        As[(aq * 4 + 3) * FLDS + arow] = avv.w;
        *(float4*)&Bs[brow * FLDS + bq * 4] = bvv;
        __syncthreads();
        #pragma unroll
        for (int k = 0; k < FBK; ++k) {
            const float4 a0 = *(const float4*)&As[k * FLDS + (ty << 2)];
            const float4 a1 = *(const float4*)&As[k * FLDS + 64 + (ty << 2)];
            const float4 b0 = *(const float4*)&Bs[k * FLDS + (tx << 2)];
            const float4 b1r = *(const float4*)&Bs[k * FLDS + 64 + (tx << 2)];
            const float ar[2][4] = {{a0.x,a0.y,a0.z,a0.w},{a1.x,a1.y,a1.z,a1.w}};
            const float br[2][4] = {{b0.x,b0.y,b0.z,b0.w},{b1r.x,b1r.y,b1r.z,b1r.w}};
            #pragma unroll
            for (int ri = 0; ri < 2; ++ri)
                #pragma unroll
                for (int i = 0; i < 4; ++i)
                    #pragma unroll
                    for (int rj = 0; rj < 2; ++rj)
                        #pragma unroll
                        for (int j = 0; j < 4; ++j)
                            acc[ri][rj][i][j] = fmaf(ar[ri][i], br[rj][j], acc[ri][rj][i][j]);
        }
        Aptr += FBK;
        Bptr += FBK * H_;
    }

    float ps[2][4][C_];
    #pragma unroll
    for (int ri = 0; ri < 2; ++ri)
        #pragma unroll
        for (int i = 0; i < 4; ++i)
            #pragma unroll
            for (int cc = 0; cc < C_; ++cc) ps[ri][i][cc] = 0.f;

    #pragma unroll
    for (int rj = 0; rj < 2; ++rj)
        #pragma unroll
        for (int j = 0; j < 4; ++j) {
            const int nl = rj * 64 + (tx << 2) + j;
            const float bj = b1[n0 + nl];
            float w2c[C_];
            #pragma unroll
            for (int cc = 0; cc < C_; ++cc) w2c[cc] = w2s[nl][cc];
            #pragma unroll
            for (int ri = 0; ri < 2; ++ri)
                #pragma unroll
                for (int i = 0; i < 4; ++i) {
                    float h = acc[ri][rj][i][j] + bj;
                    h = h > 0.f ? h : 0.f;
                    #pragma unroll
                    for (int cc = 0; cc < C_; ++cc)
                        ps[ri][i][cc] = fmaf(h, w2c[cc], ps[ri][i][cc]);
                }
        }

    #pragma unroll
    for (int off = 1; off < 16; off <<= 1)
        #pragma unroll
        for (int ri = 0; ri < 2; ++ri)
            #pragma unroll
            for (int i = 0; i < 4; ++i)
                #pragma unroll
                for (int cc = 0; cc < C_; ++cc)
                    ps[ri][i][cc] += __shfl_xor(ps[ri][i][cc], off, 64);

    if (tx == 0)
        #pragma unroll
        for (int ri = 0; ri < 2; ++ri)
            #pragma unroll
            for (int i = 0; i < 4; ++i) {
                const int m = m0 + ri * 64 + (ty << 2) + i;
                #pragma unroll
                for (int cc = 0; cc < C_; ++cc)
                    atomicAdd(&pot[m * C_ + cc], ps[ri][i][cc]);
            }
}

// =========================================================================
// Kernel 3: Viterbi via max-plus associative scan (verified).
// =========================================================================
__global__ __launch_bounds__(64) void viterbi_kernel(
    const float* __restrict__ pot, const float* __restrict__ trans,
    const int* __restrict__ mask, float* __restrict__ decoded,
    float* __restrict__ seqlen, float* __restrict__ chain_out)
{
    const int b = blockIdx.x;
    const int lane = threadIdx.x;

    __shared__ float pl[S_ * C_];
    __shared__ unsigned int bpk[S_];
    __shared__ unsigned int gseg[64];
    __shared__ int bt[64];
    __shared__ int dec_s[S_];
    __shared__ int s_last;

    const float* pb = pot + b * (S_ * C_);
    for (int i = lane; i < S_ * C_; i += 64) pl[i] = pb[i];

    int mcnt = 0;
    const int* mb = mask + b * S_;
    for (int i = lane; i < S_; i += 64) mcnt += (mb[i] != 0) ? 1 : 0;
    #pragma unroll
    for (int off = 32; off >= 1; off >>= 1) mcnt += __shfl_xor(mcnt, off, 64);

    if (b == 0 && lane < C_ * C_) chain_out[lane] = trans[lane];

    float tr[C_][C_];
    #pragma unroll
    for (int p = 0; p < C_; ++p)
        #pragma unroll
        for (int c = 0; c < C_; ++c) tr[p][c] = trans[p * C_ + c];

    __syncthreads();

    const float NEG = -1.0e30f;

    float G[C_][C_];
    #pragma unroll
    for (int c = 0; c < C_; ++c)
        #pragma unroll
        for (int p = 0; p < C_; ++p) G[c][p] = (c == p) ? 0.f : NEG;

    for (int j = 1; j <= 8; ++j) {
        const int t = 8 * lane + j;
        if (t < S_) {
            float ng[C_][C_];
            #pragma unroll
            for (int c = 0; c < C_; ++c) {
                const float pc = pl[t * C_ + c];
                #pragma unroll
                for (int p = 0; p < C_; ++p) {
                    float m = tr[0][c] + G[0][p];
                    #pragma unroll
                    for (int q = 1; q < C_; ++q)
                        m = fmaxf(m, tr[q][c] + G[q][p]);
                    ng[c][p] = m + pc;
                }
            }
            #pragma unroll
            for (int c = 0; c < C_; ++c)
                #pragma unroll
                for (int p = 0; p < C_; ++p) G[c][p] = ng[c][p];
        }
    }

    #pragma unroll
    for (int d = 1; d < 64; d <<= 1) {
        float Q[C_][C_];
        #pragma unroll
        for (int q = 0; q < C_; ++q)
            #pragma unroll
            for (int p = 0; p < C_; ++p) Q[q][p] = __shfl_up(G[q][p], d, 64);
        if (lane >= d) {
            float ng[C_][C_];
            #pragma unroll
            for (int c = 0; c < C_; ++c)
                #pragma unroll
                for (int p = 0; p < C_; ++p) {
                    float m = G[c][0] + Q[0][p];
                    #pragma unroll
                    for (int q = 1; q < C_; ++q)
                        m = fmaxf(m, G[c][q] + Q[q][p]);
                    ng[c][p] = m;
                }
            #pragma unroll
            for (int c = 0; c < C_; ++c)
                #pragma unroll
                for (int p = 0; p < C_; ++p) G[c][p] = ng[c][p];
        }
    }

    float a[C_];
    {
        float E[C_][C_];
        #pragma unroll
        for (int c = 0; c < C_; ++c)
            #pragma unroll
            for (int p = 0; p < C_; ++p) E[c][p] = __shfl_up(G[c][p], 1, 64);
        float a0[C_];
        #pragma unroll
        for (int c = 0; c < C_; ++c) a0[c] = pl[c];
        if (lane == 0) {
            #pragma unroll
            for (int c = 0; c < C_; ++c) a[c] = a0[c];
        } else {
            #pragma unroll
            for (int c = 0; c < C_; ++c) {
                float m = E[c][0] + a0[0];
                #pragma unroll
                for (int q = 1; q < C_; ++q) m = fmaxf(m, E[c][q] + a0[q]);
                a[c] = m;
            }
        }
    }

    for (int j = 1; j <= 8; ++j) {
        const int t = 8 * lane + j;
        if (t < S_) {
            unsigned int mpack = 0;
            float na[C_];
            #pragma unroll
            for (int c = 0; c < C_; ++c) {
                float best = a[0] + tr[0][c];
                int arg = 0;
                #pragma unroll
                for (int p = 1; p < C_; ++p) {
                    const float s = a[p] + tr[p][c];
                    if (s > best) { best = s; arg = p; }
                }
                mpack |= (unsigned int)arg << (3 * c);
                na[c] = best + pl[t * C_ + c];
            }
            bpk[t] = mpack;
            #pragma unroll
            for (int c = 0; c < C_; ++c) a[c] = na[c];
        }
    }

    if (lane == 63) {
        float best = a[0];
        int arg = 0;
        #pragma unroll
        for (int p = 1; p < C_; ++p)
            if (a[p] > best) { best = a[p]; arg = p; }
        s_last = arg;
    }
    if (lane == 0) bpk[0] = 0;
    __syncthreads();

    const int last = s_last;

    unsigned int g = 0u | (1u << 3) | (2u << 6) | (3u << 9) | (4u << 12);
    #pragma unroll
    for (int j = 7; j >= 0; --j) {
        const int t = 8 * lane + j;
        if (t >= 1) {
            const unsigned int m = bpk[t];
            unsigned int ng = 0;
            #pragma unroll
            for (int x = 0; x < C_; ++x) {
                const unsigned int gx = (g >> (3 * x)) & 7u;
                ng |= ((m >> (3 * gx)) & 7u) << (3 * x);
            }
            g = ng;
        }
    }
    gseg[lane] = g;
    __syncthreads();

    if (lane == 0) {
        int cur = last;
        for (int l = 63; l >= 0; --l) {
            bt[l] = cur;
            cur = (int)((gseg[l] >> (3 * cur)) & 7u);
        }
        seqlen[b] = (float)mcnt;
    }
    __syncthreads();

    {
        int tag = bt[lane];
        const int t0 = 8 * lane;
        dec_s[t0 + 7] = tag;
        #pragma unroll
        for (int t = t0 + 7; t >= t0 + 1; --t) {
            tag = (int)((bpk[t] >> (3 * tag)) & 7u);
            dec_s[t - 1] = tag;
        }
    }
    __syncthreads();

    float* db = decoded + b * S_;
    for (int i = lane; i < S_; i += 64) db[i] = (float)dec_s[i];
}

// =========================================================================
extern "C" void kernel_launch(void* const* d_in, const int* in_sizes, int n_in,
                              void* d_out, int out_size, void* d_ws, size_t ws_size,
                              hipStream_t stream) {
    const float* hs    = (const float*)d_in[0];
    const int*   mask  = (const int*)  d_in[1];
    const float* W1    = (const float*)d_in[2];
    const float* b1    = (const float*)d_in[3];
    const float* W2    = (const float*)d_in[4];
    const float* b2    = (const float*)d_in[5];
    const float* chain = (const float*)d_in[6];
    const float* lb    = (const float*)d_in[7];
    const float* rb    = (const float*)d_in[8];

    float* out      = (float*)d_out;
    float* decoded  = out;
    float* pot      = out + M_;
    float* seq      = out + M_ + M_ * C_;
    float* chainout = seq + B_;

    const size_t need = (size_t)W1T_ELEMS * 2 + (size_t)PART2_ELEMS * 4;   // ~2.5 MB

    if (ws_size >= need) {
        unsigned short* w1t = (unsigned short*)d_ws;
        float* part = (float*)(w1t + W1T_ELEMS);
        dim3 pgrid(H_ / 32, D_ / 32);
        prep_w1_kernel<<<pgrid, 256, 0, stream>>>(W1, w1t);
        gemm_r256_kernel<<<256, 1024, 0, stream>>>(hs, w1t, b1, W2, part);
        reduce_pot_kernel<<<(M_ * C_ + 255) / 256, 256, 0, stream>>>(
            part, b2, lb, rb, pot);
    } else {
        init_pot_kernel<<<(M_ * C_ + 255) / 256, 256, 0, stream>>>(b2, lb, rb, pot);
        dim3 grid(H_ / 128, M_ / 128);
        gemm_relu_pot_kernel<<<grid, 256, 0, stream>>>(hs, W1, b1, W2, pot);
    }

    viterbi_kernel<<<B_, 64, 0, stream>>>(pot, chain, mask, decoded, seq, chainout);
}

// Round 12
// 259.630 us; speedup vs baseline: 1.6111x; 1.6111x over previous
//
#include <hip/hip_runtime.h>

// Problem constants
#define B_  64
#define S_  512
#define D_  768
#define H_  768
#define C_  5
#define M_  (B_ * S_)        // 32768 rows

typedef float f32x4 __attribute__((ext_vector_type(4)));
typedef short short8 __attribute__((ext_vector_type(8)));   // bf16x8 MFMA operand

#define W1T_ELEMS (D_ * H_)          // 589824  (bf16: 1.18 MB)
#define PART2_ELEMS (2 * M_ * C_)    // 327680 floats = 1.31 MB

__device__ __forceinline__ unsigned short f2bf(float f) {
    unsigned int u = __float_as_uint(f);
    u += 0x7FFFu + ((u >> 16) & 1u);     // RNE
    return (unsigned short)(u >> 16);
}

// =========================================================================
// prep: W1 [k][n] fp32 -> w1t [n][k] bf16 (LDS-tiled transpose). ~3 us.
// =========================================================================
__global__ __launch_bounds__(256) void prep_w1_kernel(
    const float* __restrict__ W1, unsigned short* __restrict__ w1t)
{
    __shared__ float t[32][33];
    const int bx = blockIdx.x, by = blockIdx.y;
    const int lx = threadIdx.x & 31, ly = threadIdx.x >> 5;
    #pragma unroll
    for (int j = 0; j < 4; ++j)
        t[ly + 8 * j][lx] = W1[(by * 32 + ly + 8 * j) * H_ + bx * 32 + lx];
    __syncthreads();
    #pragma unroll
    for (int j = 0; j < 4; ++j)
        w1t[(size_t)(bx * 32 + ly + 8 * j) * D_ + by * 32 + lx] = f2bf(t[lx][ly + 8 * j]);
}

__global__ __launch_bounds__(256) void init_pot_kernel(
    const float* __restrict__ b2, const float* __restrict__ lb,
    const float* __restrict__ rb, float* __restrict__ pot)
{
    const int idx = blockIdx.x * 256 + threadIdx.x;
    if (idx < M_ * C_) {
        const int c = idx % C_;
        const int t = (idx / C_) & (S_ - 1);
        float v = b2[c];
        if (t == 0)      v += lb[c];
        if (t == S_ - 1) v += rb[c];
        pot[idx] = v;
    }
}

// =========================================================================
// Kernel 2 (R12): 256 rows x half-N (384 cols), 512 threads, acc[16][3].
//
// R11 post-mortem: 1024 threads (4 waves/SIMD) caps VGPR at 128; kernel
// needed ~156 -> total spill (VGPR 64, WRITE 510 MB scratch, 280 us).
// Rule: stay at 512 threads (2 waves/SIMD, cap 256). R12 reaches the same
// 351 MB byte bill with wave tile 256 rows x 48 cols: acc[16][3]=192 VGPR
// + bfr[3] 12 + af[8]-at-a-time 32 ~= 236 peak < 256. Structure = R10's
// proven machinery: A fp32->bf16 reg-convert -> LDS (2x32KB dbuf, ONE
// barrier/K-tile), B streamed L2->regs via 32-bit voffsets + imm offsets
// (no per-iter address math), verified subtile layout (af = At[(mi*2+kh)
// *512 + lane*8]). No async-split (would blow the reg cap); staging is
// fully before compute so lifetimes don't overlap. Output: wave partials
// -> pp -> plain part stores; reduce_pot folds b2/boundaries. No atomics.
// Bytes: X 200 (2 passes, 2nd L3-served) + B 1.18MB*128 = 151 -> 351 MB.
// Spill canary: WRITE_SIZE must stay ~1.3 MB.
// =========================================================================
__global__ __launch_bounds__(512) void gemm_r256b_kernel(
    const float* __restrict__ X,              // [M_, D_] fp32
    const unsigned short* __restrict__ w1t,   // [H_, D_] bf16 (n-major)
    const float* __restrict__ b1,
    const float* __restrict__ W2,             // [H_, C_]
    float* __restrict__ part)                 // [2][M_][C_] partials
{
    // A tile: [2 buf][256 rows x 64 k] bf16, 32 subtiles of 512 shorts:
    //   off = ((row>>4)*2 + (k>>5))*512 + (((k>>3)&3)*16 + (row&15))*8
    __shared__ __align__(16) unsigned short At[2][16384];   // 64 KB
    __shared__ float pp[8][256][C_];                        // 40 KB

    const int tid  = threadIdx.x;
    const int lane = tid & 63, w = tid >> 6;       // wave 0..7
    const int i15  = lane & 15, quad = lane >> 4;

    const int bid  = blockIdx.x;
    const int nh   = bid & 1;           // n-half 0..1
    const int rowb = (bid >> 1) * 256;  // 128 row-groups
    const int ncol0 = nh * 384 + w * 48;   // wave's 48 cols

    // B: 32-bit byte offsets from uniform base (SGPR saddr + voffset form);
    // per-(kt,kh) delta is an immediate (kt*128 + kh*64 <= 1472 B).
    const char* w1tB = (const char*)w1t;
    int boff[3];
    #pragma unroll
    for (int ni = 0; ni < 3; ++ni)
        boff[ni] = ((ncol0 + ni * 16 + i15) * D_ + quad * 8) * 2;

    // A staging map: thread handles row = tid>>1, k-half (tid&1)*32 floats
    const int arow  = tid >> 1;             // 0..255
    const int khalf = (tid & 1) * 32;
    const float* aBase = X + (size_t)(rowb + arow) * D_ + khalf;
    const int bo = (tid & 1) * 4;           // base k-octet (4 octets/thread)
    int adst[4];
    #pragma unroll
    for (int j2 = 0; j2 < 4; ++j2) {
        const int o = bo + j2;
        adst[j2] = ((arow >> 4) * 2 + (o >> 2)) * 512 + ((o & 3) * 16 + (arow & 15)) * 8;
    }

    f32x4 acc[16][3];
    #pragma unroll
    for (int mi = 0; mi < 16; ++mi)
        #pragma unroll
        for (int ni = 0; ni < 3; ++ni)
            acc[mi][ni] = (f32x4){0.f, 0.f, 0.f, 0.f};

    // stage K-tile KT (32 floats/thread -> 4 uint4 bf16 subtile writes)
    #define STAGE(KT, BUF) do {                                              \
        _Pragma("unroll")                                                    \
        for (int j2 = 0; j2 < 4; ++j2) {                                     \
            const float4 fa = *(const float4*)(aBase + (KT) * 64 + j2 * 8);  \
            const float4 fb = *(const float4*)(aBase + (KT) * 64 + j2 * 8 + 4); \
            union { unsigned short u[8]; uint4 v; } o_;                      \
            o_.u[0] = f2bf(fa.x); o_.u[1] = f2bf(fa.y);                      \
            o_.u[2] = f2bf(fa.z); o_.u[3] = f2bf(fa.w);                      \
            o_.u[4] = f2bf(fb.x); o_.u[5] = f2bf(fb.y);                      \
            o_.u[6] = f2bf(fb.z); o_.u[7] = f2bf(fb.w);                      \
            *(uint4*)&At[BUF][adst[j2]] = o_.v;                              \
        }                                                                    \
    } while (0)

    // ---- prologue: tile 0 -> buf 0 ----
    STAGE(0, 0);
    __syncthreads();

    // ---- main loop: 12 K-tiles, ONE barrier each (dbuf) ----
    for (int kt = 0; kt < 12; ++kt) {
        const int cur = kt & 1;
        if (kt < 11) STAGE(kt + 1, cur ^ 1);   // regs dead before compute

        #pragma unroll
        for (int kh = 0; kh < 2; ++kh) {
            short8 bfr[3];
            #pragma unroll
            for (int ni = 0; ni < 3; ++ni)
                bfr[ni] = *(const short8*)(w1tB + boff[ni] + kt * 128 + kh * 64);
            #pragma unroll
            for (int mh = 0; mh < 2; ++mh) {
                short8 af[8];
                #pragma unroll
                for (int j = 0; j < 8; ++j)
                    af[j] = *(const short8*)
                        &At[cur][((mh * 8 + j) * 2 + kh) * 512 + lane * 8];
                #pragma unroll
                for (int ni = 0; ni < 3; ++ni)
                    #pragma unroll
                    for (int j = 0; j < 8; ++j)
                        acc[mh * 8 + j][ni] = __builtin_amdgcn_mfma_f32_16x16x32_bf16(
                            af[j], bfr[ni], acc[mh * 8 + j][ni], 0, 0, 0);
            }
        }
        __syncthreads();
    }

    // ---- epilogue: relu(h+b1)@W2, wave-partial -> pp -> part store ----
    float b1v[3], w2v[3][C_];
    #pragma unroll
    for (int ni = 0; ni < 3; ++ni) {
        const int col = ncol0 + ni * 16 + i15;
        b1v[ni] = b1[col];
        #pragma unroll
        for (int cc = 0; cc < C_; ++cc) w2v[ni][cc] = W2[col * C_ + cc];
    }

    #pragma unroll
    for (int mi = 0; mi < 16; ++mi) {
        float ps[4][C_];
        #pragma unroll
        for (int r = 0; r < 4; ++r)
            #pragma unroll
            for (int cc = 0; cc < C_; ++cc) ps[r][cc] = 0.f;

        #pragma unroll
        for (int ni = 0; ni < 3; ++ni)
            #pragma unroll
            for (int r = 0; r < 4; ++r) {
                float hh = acc[mi][ni][r] + b1v[ni];
                hh = hh > 0.f ? hh : 0.f;
                #pragma unroll
                for (int cc = 0; cc < C_; ++cc)
                    ps[r][cc] = fmaf(hh, w2v[ni][cc], ps[r][cc]);
            }

        // reduce over the 16 cols held across i15 lanes (quad = rows)
        #pragma unroll
        for (int off = 1; off < 16; off <<= 1)
            #pragma unroll
            for (int r = 0; r < 4; ++r)
                #pragma unroll
                for (int cc = 0; cc < C_; ++cc)
                    ps[r][cc] += __shfl_xor(ps[r][cc], off, 64);

        if (i15 == 0) {
            #pragma unroll
            for (int r = 0; r < 4; ++r) {
                const int row = mi * 16 + quad * 4 + r;   // 0..255
                #pragma unroll
                for (int cc = 0; cc < C_; ++cc)
                    pp[w][row][cc] = ps[r][cc];
            }
        }
    }
    __syncthreads();

    for (int idx = tid; idx < 256 * C_; idx += 512) {
        const int row = idx / C_, cc = idx % C_;
        float s = 0.f;
        #pragma unroll
        for (int wv = 0; wv < 8; ++wv)
            s += pp[wv][row][cc];
        part[((size_t)nh * M_ + rowb + row) * C_ + cc] = s;
    }
    #undef STAGE
}

// =========================================================================
// Kernel 2b: reduce 2 partials + b2/boundaries -> pot
// =========================================================================
__global__ __launch_bounds__(256) void reduce_pot_kernel(
    const float* __restrict__ part, const float* __restrict__ b2,
    const float* __restrict__ lb, const float* __restrict__ rb,
    float* __restrict__ pot)
{
    const int idx = blockIdx.x * 256 + threadIdx.x;
    if (idx < M_ * C_) {
        const int c = idx % C_;
        const int t = (idx / C_) & (S_ - 1);
        float v = b2[c];
        if (t == 0)      v += lb[c];
        if (t == S_ - 1) v += rb[c];
        v += part[idx] + part[(size_t)(M_ * C_) + idx];
        pot[idx] = v;
    }
}

// =========================================================================
// Last-resort fp32 GEMM if ws too small
// =========================================================================
#define FBK 8
#define FLDS 132
__global__ __launch_bounds__(256) void gemm_relu_pot_kernel(
    const float* __restrict__ X, const float* __restrict__ W1,
    const float* __restrict__ b1, const float* __restrict__ W2,
    float* __restrict__ pot)
{
    __shared__ float As[FBK * FLDS];
    __shared__ float Bs[FBK * FLDS];
    __shared__ float w2s[128][C_];

    const int tid = threadIdx.x;
    const int tx = tid & 15, ty = tid >> 4;
    const int m0 = blockIdx.y * 128, n0 = blockIdx.x * 128;

    for (int idx = tid; idx < 128 * C_; idx += 256)
        w2s[idx / C_][idx % C_] = W2[(n0 + idx / C_) * C_ + idx % C_];

    float acc[2][2][4][4];
    #pragma unroll
    for (int a = 0; a < 2; ++a)
        #pragma unroll
        for (int b = 0; b < 2; ++b)
            #pragma unroll
            for (int i = 0; i < 4; ++i)
                #pragma unroll
                for (int j = 0; j < 4; ++j) acc[a][b][i][j] = 0.f;

    const int arow = tid >> 1, aq = tid & 1;
    const int brow = tid >> 5, bq = tid & 31;
    const float* Aptr = X + (m0 + arow) * D_ + aq * 4;
    const float* Bptr = W1 + brow * H_ + n0 + bq * 4;

    for (int kt = 0; kt < D_; kt += FBK) {
        const float4 avv = *(const float4*)Aptr;
        const float4 bvv = *(const float4*)Bptr;
        __syncthreads();
        As[(aq * 4 + 0) * FLDS + arow] = avv.x;
        As[(aq * 4 + 1) * FLDS + arow] = avv.y;
        As[(aq * 4 + 2) * FLDS + arow] = avv.z;
        As[(aq * 4 + 3) * FLDS + arow] = avv.w;
        *(float4*)&Bs[brow * FLDS + bq * 4] = bvv;
        __syncthreads();
        #pragma unroll
        for (int k = 0; k < FBK; ++k) {
            const float4 a0 = *(const float4*)&As[k * FLDS + (ty << 2)];
            const float4 a1 = *(const float4*)&As[k * FLDS + 64 + (ty << 2)];
            const float4 b0 = *(const float4*)&Bs[k * FLDS + (tx << 2)];
            const float4 b1r = *(const float4*)&Bs[k * FLDS + 64 + (tx << 2)];
            const float ar[2][4] = {{a0.x,a0.y,a0.z,a0.w},{a1.x,a1.y,a1.z,a1.w}};
            const float br[2][4] = {{b0.x,b0.y,b0.z,b0.w},{b1r.x,b1r.y,b1r.z,b1r.w}};
            #pragma unroll
            for (int ri = 0; ri < 2; ++ri)
                #pragma unroll
                for (int i = 0; i < 4; ++i)
                    #pragma unroll
                    for (int rj = 0; rj < 2; ++rj)
                        #pragma unroll
                        for (int j = 0; j < 4; ++j)
                            acc[ri][rj][i][j] = fmaf(ar[ri][i], br[rj][j], acc[ri][rj][i][j]);
        }
        Aptr += FBK;
        Bptr += FBK * H_;
    }

    float ps[2][4][C_];
    #pragma unroll
    for (int ri = 0; ri < 2; ++ri)
        #pragma unroll
        for (int i = 0; i < 4; ++i)
            #pragma unroll
            for (int cc = 0; cc < C_; ++cc) ps[ri][i][cc] = 0.f;

    #pragma unroll
    for (int rj = 0; rj < 2; ++rj)
        #pragma unroll
        for (int j = 0; j < 4; ++j) {
            const int nl = rj * 64 + (tx << 2) + j;
            const float bj = b1[n0 + nl];
            float w2c[C_];
            #pragma unroll
            for (int cc = 0; cc < C_; ++cc) w2c[cc] = w2s[nl][cc];
            #pragma unroll
            for (int ri = 0; ri < 2; ++ri)
                #pragma unroll
                for (int i = 0; i < 4; ++i) {
                    float h = acc[ri][rj][i][j] + bj;
                    h = h > 0.f ? h : 0.f;
                    #pragma unroll
                    for (int cc = 0; cc < C_; ++cc)
                        ps[ri][i][cc] = fmaf(h, w2c[cc], ps[ri][i][cc]);
                }
        }

    #pragma unroll
    for (int off = 1; off < 16; off <<= 1)
        #pragma unroll
        for (int ri = 0; ri < 2; ++ri)
            #pragma unroll
            for (int i = 0; i < 4; ++i)
                #pragma unroll
                for (int cc = 0; cc < C_; ++cc)
                    ps[ri][i][cc] += __shfl_xor(ps[ri][i][cc], off, 64);

    if (tx == 0)
        #pragma unroll
        for (int ri = 0; ri < 2; ++ri)
            #pragma unroll
            for (int i = 0; i < 4; ++i) {
                const int m = m0 + ri * 64 + (ty << 2) + i;
                #pragma unroll
                for (int cc = 0; cc < C_; ++cc)
                    atomicAdd(&pot[m * C_ + cc], ps[ri][i][cc]);
            }
}

// =========================================================================
// Kernel 3: Viterbi via max-plus associative scan (verified).
// =========================================================================
__global__ __launch_bounds__(64) void viterbi_kernel(
    const float* __restrict__ pot, const float* __restrict__ trans,
    const int* __restrict__ mask, float* __restrict__ decoded,
    float* __restrict__ seqlen, float* __restrict__ chain_out)
{
    const int b = blockIdx.x;
    const int lane = threadIdx.x;

    __shared__ float pl[S_ * C_];
    __shared__ unsigned int bpk[S_];
    __shared__ unsigned int gseg[64];
    __shared__ int bt[64];
    __shared__ int dec_s[S_];
    __shared__ int s_last;

    const float* pb = pot + b * (S_ * C_);
    for (int i = lane; i < S_ * C_; i += 64) pl[i] = pb[i];

    int mcnt = 0;
    const int* mb = mask + b * S_;
    for (int i = lane; i < S_; i += 64) mcnt += (mb[i] != 0) ? 1 : 0;
    #pragma unroll
    for (int off = 32; off >= 1; off >>= 1) mcnt += __shfl_xor(mcnt, off, 64);

    if (b == 0 && lane < C_ * C_) chain_out[lane] = trans[lane];

    float tr[C_][C_];
    #pragma unroll
    for (int p = 0; p < C_; ++p)
        #pragma unroll
        for (int c = 0; c < C_; ++c) tr[p][c] = trans[p * C_ + c];

    __syncthreads();

    const float NEG = -1.0e30f;

    float G[C_][C_];
    #pragma unroll
    for (int c = 0; c < C_; ++c)
        #pragma unroll
        for (int p = 0; p < C_; ++p) G[c][p] = (c == p) ? 0.f : NEG;

    for (int j = 1; j <= 8; ++j) {
        const int t = 8 * lane + j;
        if (t < S_) {
            float ng[C_][C_];
            #pragma unroll
            for (int c = 0; c < C_; ++c) {
                const float pc = pl[t * C_ + c];
                #pragma unroll
                for (int p = 0; p < C_; ++p) {
                    float m = tr[0][c] + G[0][p];
                    #pragma unroll
                    for (int q = 1; q < C_; ++q)
                        m = fmaxf(m, tr[q][c] + G[q][p]);
                    ng[c][p] = m + pc;
                }
            }
            #pragma unroll
            for (int c = 0; c < C_; ++c)
                #pragma unroll
                for (int p = 0; p < C_; ++p) G[c][p] = ng[c][p];
        }
    }

    #pragma unroll
    for (int d = 1; d < 64; d <<= 1) {
        float Q[C_][C_];
        #pragma unroll
        for (int q = 0; q < C_; ++q)
            #pragma unroll
            for (int p = 0; p < C_; ++p) Q[q][p] = __shfl_up(G[q][p], d, 64);
        if (lane >= d) {
            float ng[C_][C_];
            #pragma unroll
            for (int c = 0; c < C_; ++c)
                #pragma unroll
                for (int p = 0; p < C_; ++p) {
                    float m = G[c][0] + Q[0][p];
                    #pragma unroll
                    for (int q = 1; q < C_; ++q)
                        m = fmaxf(m, G[c][q] + Q[q][p]);
                    ng[c][p] = m;
                }
            #pragma unroll
            for (int c = 0; c < C_; ++c)
                #pragma unroll
                for (int p = 0; p < C_; ++p) G[c][p] = ng[c][p];
        }
    }

    float a[C_];
    {
        float E[C_][C_];
        #pragma unroll
        for (int c = 0; c < C_; ++c)
            #pragma unroll
            for (int p = 0; p < C_; ++p) E[c][p] = __shfl_up(G[c][p], 1, 64);
        float a0[C_];
        #pragma unroll
        for (int c = 0; c < C_; ++c) a0[c] = pl[c];
        if (lane == 0) {
            #pragma unroll
            for (int c = 0; c < C_; ++c) a[c] = a0[c];
        } else {
            #pragma unroll
            for (int c = 0; c < C_; ++c) {
                float m = E[c][0] + a0[0];
                #pragma unroll
                for (int q = 1; q < C_; ++q) m = fmaxf(m, E[c][q] + a0[q]);
                a[c] = m;
            }
        }
    }

    for (int j = 1; j <= 8; ++j) {
        const int t = 8 * lane + j;
        if (t < S_) {
            unsigned int mpack = 0;
            float na[C_];
            #pragma unroll
            for (int c = 0; c < C_; ++c) {
                float best = a[0] + tr[0][c];
                int arg = 0;
                #pragma unroll
                for (int p = 1; p < C_; ++p) {
                    const float s = a[p] + tr[p][c];
                    if (s > best) { best = s; arg = p; }
                }
                mpack |= (unsigned int)arg << (3 * c);
                na[c] = best + pl[t * C_ + c];
            }
            bpk[t] = mpack;
            #pragma unroll
            for (int c = 0; c < C_; ++c) a[c] = na[c];
        }
    }

    if (lane == 63) {
        float best = a[0];
        int arg = 0;
        #pragma unroll
        for (int p = 1; p < C_; ++p)
            if (a[p] > best) { best = a[p]; arg = p; }
        s_last = arg;
    }
    if (lane == 0) bpk[0] = 0;
    __syncthreads();

    const int last = s_last;

    unsigned int g = 0u | (1u << 3) | (2u << 6) | (3u << 9) | (4u << 12);
    #pragma unroll
    for (int j = 7; j >= 0; --j) {
        const int t = 8 * lane + j;
        if (t >= 1) {
            const unsigned int m = bpk[t];
            unsigned int ng = 0;
            #pragma unroll
            for (int x = 0; x < C_; ++x) {
                const unsigned int gx = (g >> (3 * x)) & 7u;
                ng |= ((m >> (3 * gx)) & 7u) << (3 * x);
            }
            g = ng;
        }
    }
    gseg[lane] = g;
    __syncthreads();

    if (lane == 0) {
        int cur = last;
        for (int l = 63; l >= 0; --l) {
            bt[l] = cur;
            cur = (int)((gseg[l] >> (3 * cur)) & 7u);
        }
        seqlen[b] = (float)mcnt;
    }
    __syncthreads();

    {
        int tag = bt[lane];
        const int t0 = 8 * lane;
        dec_s[t0 + 7] = tag;
        #pragma unroll
        for (int t = t0 + 7; t >= t0 + 1; --t) {
            tag = (int)((bpk[t] >> (3 * tag)) & 7u);
            dec_s[t - 1] = tag;
        }
    }
    __syncthreads();

    float* db = decoded + b * S_;
    for (int i = lane; i < S_; i += 64) db[i] = (float)dec_s[i];
}

// =========================================================================
extern "C" void kernel_launch(void* const* d_in, const int* in_sizes, int n_in,
                              void* d_out, int out_size, void* d_ws, size_t ws_size,
                              hipStream_t stream) {
    const float* hs    = (const float*)d_in[0];
    const int*   mask  = (const int*)  d_in[1];
    const float* W1    = (const float*)d_in[2];
    const float* b1    = (const float*)d_in[3];
    const float* W2    = (const float*)d_in[4];
    const float* b2    = (const float*)d_in[5];
    const float* chain = (const float*)d_in[6];
    const float* lb    = (const float*)d_in[7];
    const float* rb    = (const float*)d_in[8];

    float* out      = (float*)d_out;
    float* decoded  = out;
    float* pot      = out + M_;
    float* seq      = out + M_ + M_ * C_;
    float* chainout = seq + B_;

    const size_t need = (size_t)W1T_ELEMS * 2 + (size_t)PART2_ELEMS * 4;   // ~2.5 MB

    if (ws_size >= need) {
        unsigned short* w1t = (unsigned short*)d_ws;
        float* part = (float*)(w1t + W1T_ELEMS);
        dim3 pgrid(H_ / 32, D_ / 32);
        prep_w1_kernel<<<pgrid, 256, 0, stream>>>(W1, w1t);
        gemm_r256b_kernel<<<256, 512, 0, stream>>>(hs, w1t, b1, W2, part);
        reduce_pot_kernel<<<(M_ * C_ + 255) / 256, 256, 0, stream>>>(
            part, b2, lb, rb, pot);
    } else {
        init_pot_kernel<<<(M_ * C_ + 255) / 256, 256, 0, stream>>>(b2, lb, rb, pot);
        dim3 grid(H_ / 128, M_ / 128);
        gemm_relu_pot_kernel<<<grid, 256, 0, stream>>>(hs, W1, b1, W2, pot);
    }

    viterbi_kernel<<<B_, 64, 0, stream>>>(pot, chain, mask, decoded, seq, chainout);
}